// Round 2
// baseline (1736.623 us; speedup 1.0000x reference)
//
#include <hip/hip_runtime.h>

#define BB 16
#define NV 1024
#define NH 1024
#define DD 1024

typedef _Float16 f16x8 __attribute__((ext_vector_type(8)));
typedef _Float16 f16x4 __attribute__((ext_vector_type(4)));
typedef float f32x4 __attribute__((ext_vector_type(4)));

// ---------------- cast fp32 -> fp16 ----------------
__global__ __launch_bounds__(256) void cast_k(const float* __restrict__ in,
                                              _Float16* __restrict__ out, long n4) {
  long i = (long)blockIdx.x * 256 + threadIdx.x;
  long stride = (long)gridDim.x * 256;
  for (; i < n4; i += stride) {
    float4 x = ((const float4*)in)[i];
    f16x4 o;
    o[0] = (_Float16)x.x; o[1] = (_Float16)x.y;
    o[2] = (_Float16)x.z; o[3] = (_Float16)x.w;
    ((f16x4*)out)[i] = o;
  }
}

// ---------------- split fp32 -> (hi, lo) fp16 pair ----------------
__global__ __launch_bounds__(256) void split_k(const float* __restrict__ in,
                                               _Float16* __restrict__ hi,
                                               _Float16* __restrict__ lo, long n4) {
  long i = (long)blockIdx.x * 256 + threadIdx.x;
  long stride = (long)gridDim.x * 256;
  for (; i < n4; i += stride) {
    float4 x = ((const float4*)in)[i];
    f16x4 h, l;
    h[0] = (_Float16)x.x; h[1] = (_Float16)x.y;
    h[2] = (_Float16)x.z; h[3] = (_Float16)x.w;
    l[0] = (_Float16)(x.x - (float)h[0]);
    l[1] = (_Float16)(x.y - (float)h[1]);
    l[2] = (_Float16)(x.z - (float)h[2]);
    l[3] = (_Float16)(x.w - (float)h[3]);
    ((f16x4*)hi)[i] = h;
    ((f16x4*)lo)[i] = l;
  }
}

// ---------------- async global->LDS (16B/lane) ----------------
__device__ inline void gl_lds16(const _Float16* g, _Float16* l) {
  __builtin_amdgcn_global_load_lds((__attribute__((address_space(1))) void*)g,
                                   (__attribute__((address_space(3))) void*)l,
                                   16, 0, 0);
}

// ---------------- NT GEMM: C[M,N] = (ACCUM? C:0) + A[M,K] * B[N,K]^T (+bias) --
// grid: (N/128, M/128, batch), block 256 (4 waves, each 64x64)
template <typename CT, bool ACCUM>
__global__ __launch_bounds__(256) void gemm_nt_k(
    const _Float16* __restrict__ A, const _Float16* __restrict__ B,
    CT* __restrict__ C, const float* __restrict__ bias,
    int N, int K, long sA, long sB, long sC) {
  __shared__ _Float16 lA[128 * 32];
  __shared__ _Float16 lB[128 * 32];
  const int tid = threadIdx.x;
  const int w = tid >> 6, l = tid & 63;
  const int bn = blockIdx.x, bm = blockIdx.y, bz = blockIdx.z;
  const _Float16* Ab = A + (long)bz * sA;
  const _Float16* Bb = B + (long)bz * sB;
  CT* Cb = C + (long)bz * sC;

  // staging: wave w stages chunks 2w,2w+1 of each tile (chunk = 16 rows x 32 cols)
  const int c0 = 2 * w;
  const int srow = l >> 2, scol = (l & 3) * 8;
  const _Float16* pA = Ab + (long)(bm * 128 + c0 * 16 + srow) * K + scol;
  const _Float16* pB = Bb + (long)(bn * 128 + c0 * 16 + srow) * K + scol;
  const long rs16 = (long)16 * K;
  _Float16* dA = lA + c0 * 16 * 32;
  _Float16* dB = lB + c0 * 16 * 32;

  f32x4 acc[4][4] = {};

  const int wm = w >> 1, wn = w & 1;
  const int fr = l & 15, fq = l >> 4;
  const int aoff = (wm * 64 + fr) * 32 + fq * 8;
  const int boff = (wn * 64 + fr) * 32 + fq * 8;

  for (int kt = 0; kt < K; kt += 32) {
    gl_lds16(pA, dA);
    gl_lds16(pA + rs16, dA + 16 * 32);
    gl_lds16(pB, dB);
    gl_lds16(pB + rs16, dB + 16 * 32);
    pA += 32; pB += 32;
    __syncthreads();
    f16x8 af[4], bf[4];
#pragma unroll
    for (int r = 0; r < 4; ++r) af[r] = *(const f16x8*)&lA[aoff + r * 16 * 32];
#pragma unroll
    for (int c = 0; c < 4; ++c) bf[c] = *(const f16x8*)&lB[boff + c * 16 * 32];
#pragma unroll
    for (int r = 0; r < 4; ++r)
#pragma unroll
      for (int c = 0; c < 4; ++c)
        acc[r][c] = __builtin_amdgcn_mfma_f32_16x16x32_f16(af[r], bf[c], acc[r][c], 0, 0, 0);
    __syncthreads();
  }

  // epilogue: C/D layout col=lane&15, row=(lane>>4)*4+e
#pragma unroll
  for (int r = 0; r < 4; ++r) {
    const int grow = bm * 128 + wm * 64 + r * 16 + fq * 4;
#pragma unroll
    for (int c = 0; c < 4; ++c) {
      const int gcol = bn * 128 + wn * 64 + c * 16 + fr;
      const float bv = bias ? bias[gcol] : 0.0f;
#pragma unroll
      for (int e = 0; e < 4; ++e) {
        const long idx = (long)(grow + e) * N + gcol;
        float prev = ACCUM ? (float)Cb[idx] : 0.0f;
        Cb[idx] = (CT)(prev + acc[r][c][e] + bv);
      }
    }
  }
}

// ---------------- apply h_mask to key rows (fp32 K) ----------------
__global__ __launch_bounds__(256) void mask_key_k(float* __restrict__ Kmat,
                                                  const int* __restrict__ hm) {
  int row = blockIdx.x * 256 + threadIdx.x;
  if (row < BB * NH && hm[row] == 0) {
    for (int d = 0; d < DD; ++d) Kmat[(long)row * DD + d] = -30000.0f;
  }
}

// ---------------- wave/block reduce helpers ----------------
__device__ inline float wave_max(float v) {
#pragma unroll
  for (int o = 32; o > 0; o >>= 1) v = fmaxf(v, __shfl_xor(v, o, 64));
  return v;
}
__device__ inline float wave_sum(float v) {
#pragma unroll
  for (int o = 32; o > 0; o >>= 1) v += __shfl_xor(v, o, 64);
  return v;
}

// ---------------- row softmax: att fp32 [rows,1024] -> P fp16 ----------------
__global__ __launch_bounds__(256) void softmax_rows_k(const float* __restrict__ att,
                                                      _Float16* __restrict__ P) {
  __shared__ float red[4];
  long row = blockIdx.x;
  int t = threadIdx.x, w = t >> 6;
  float4 x = ((const float4*)(att + row * 1024))[t];
  float m = fmaxf(fmaxf(x.x, x.y), fmaxf(x.z, x.w));
  m = wave_max(m);
  if ((t & 63) == 0) red[w] = m;
  __syncthreads();
  m = fmaxf(fmaxf(red[0], red[1]), fmaxf(red[2], red[3]));
  float e0 = expf(x.x - m), e1 = expf(x.y - m), e2 = expf(x.z - m), e3 = expf(x.w - m);
  float s = wave_sum(e0 + e1 + e2 + e3);
  __syncthreads();
  if ((t & 63) == 0) red[w] = s;
  __syncthreads();
  float inv = 1.0f / (red[0] + red[1] + red[2] + red[3]);
  f16x4 o;
  o[0] = (_Float16)(e0 * inv); o[1] = (_Float16)(e1 * inv);
  o[2] = (_Float16)(e2 * inv); o[3] = (_Float16)(e3 * inv);
  ((f16x4*)(P + row * 1024))[t] = o;
}

// ---------------- s = sigmoid(vv+hv+zz) -> z_new[:, :D]; u = s . Wu ----------------
__global__ __launch_bounds__(256) void s_u_k(const _Float16* __restrict__ Vv,
                                             const float* __restrict__ Hv,
                                             const _Float16* __restrict__ Zz,
                                             const float* __restrict__ Wu,
                                             float* __restrict__ zout,
                                             float* __restrict__ u) {
  __shared__ float red[4];
  long row = blockIdx.x;
  int t = threadIdx.x, w = t >> 6;
  f16x4 a = ((const f16x4*)(Vv + row * 1024))[t];
  float4 b = ((const float4*)(Hv + row * 1024))[t];
  f16x4 c = ((const f16x4*)(Zz + row * 1024))[t];
  float4 wu = ((const float4*)Wu)[t];
  float4 sv;
  sv.x = 1.0f / (1.0f + expf(-((float)a[0] + b.x + (float)c[0])));
  sv.y = 1.0f / (1.0f + expf(-((float)a[1] + b.y + (float)c[1])));
  sv.z = 1.0f / (1.0f + expf(-((float)a[2] + b.z + (float)c[2])));
  sv.w = 1.0f / (1.0f + expf(-((float)a[3] + b.w + (float)c[3])));
  ((float4*)(zout + row * 2048))[t] = sv;
  float part = sv.x * wu.x + sv.y * wu.y + sv.z * wu.z + sv.w * wu.w;
  part = wave_sum(part);
  if ((t & 63) == 0) red[w] = part;
  __syncthreads();
  if (t == 0) u[row] = red[0] + red[1] + red[2] + red[3];
}

// ---------------- per-batch softmax over u (masked) ----------------
__global__ __launch_bounds__(256) void u_softmax_k(const float* __restrict__ u,
                                                   const int* __restrict__ vmask,
                                                   float* __restrict__ p) {
  __shared__ float red[4];
  int b = blockIdx.x, t = threadIdx.x, w = t >> 6;
  float4 uv = ((const float4*)(u + b * 1024))[t];
  int4 mv = ((const int4*)(vmask + b * 1024))[t];
  float l0 = mv.x ? uv.x : -1e30f;
  float l1 = mv.y ? uv.y : -1e30f;
  float l2 = mv.z ? uv.z : -1e30f;
  float l3 = mv.w ? uv.w : -1e30f;
  float m = wave_max(fmaxf(fmaxf(l0, l1), fmaxf(l2, l3)));
  if ((t & 63) == 0) red[w] = m;
  __syncthreads();
  m = fmaxf(fmaxf(red[0], red[1]), fmaxf(red[2], red[3]));
  float e0 = expf(l0 - m), e1 = expf(l1 - m), e2 = expf(l2 - m), e3 = expf(l3 - m);
  float s = wave_sum(e0 + e1 + e2 + e3);
  __syncthreads();
  if ((t & 63) == 0) red[w] = s;
  __syncthreads();
  float inv = 1.0f / (red[0] + red[1] + red[2] + red[3]);
  float4 o = make_float4(e0 * inv, e1 * inv, e2 * inv, e3 * inv);
  ((float4*)(p + b * 1024))[t] = o;
}

// ---------------- f[b,d] = sum_j p[b,j] * v[b,j,d] (partials via atomics) ----------------
__global__ __launch_bounds__(256) void f_part_k(const float* __restrict__ p,
                                                const float* __restrict__ v,
                                                float* __restrict__ f) {
  int d = blockIdx.x * 256 + threadIdx.x;  // gridDim.x = 4
  int b = blockIdx.y;                      // 16
  int jc = blockIdx.z;                     // 8 chunks of 128
  const float* vb = v + ((long)b * NV + jc * 128) * DD + d;
  const float* pb = p + b * NV + jc * 128;
  float acc = 0.0f;
#pragma unroll 4
  for (int j = 0; j < 128; ++j) acc = fmaf(pb[j], vb[(long)j * DD], acc);
  atomicAdd(&f[b * DD + d], acc);
}

// ---------------- broadcast f into h_new and z_new[:, D:] ----------------
__global__ __launch_bounds__(256) void bcast_k(const float* __restrict__ f,
                                               float* __restrict__ hout,
                                               float* __restrict__ zout) {
  long idx = (long)blockIdx.x * 256 + threadIdx.x;  // 0 .. 4M-1 (float4 units)
  int d4 = (int)(idx & 255);
  long bn = idx >> 8;
  int b = (int)(bn >> 10);
  float4 val = ((const float4*)f)[(b << 8) + d4];
  ((float4*)hout)[idx] = val;
  ((float4*)zout)[bn * 512 + 256 + d4] = val;
}

// ---------------- host ----------------
extern "C" void kernel_launch(void* const* d_in, const int* in_sizes, int n_in,
                              void* d_out, int out_size, void* d_ws, size_t ws_size,
                              hipStream_t stream) {
  const float* v = (const float*)d_in[0];
  const float* h = (const float*)d_in[1];
  const float* z = (const float*)d_in[2];
  const int* v_mask = (const int*)d_in[3];
  const int* h_mask = (const int*)d_in[4];
  const float* Wv_w = (const float*)d_in[5];
  const float* Wv_b = (const float*)d_in[6];
  const float* Wh_w = (const float*)d_in[7];
  const float* qv_w = (const float*)d_in[8];
  const float* qv_b = (const float*)d_in[9];
  const float* kh_w = (const float*)d_in[10];
  const float* Wz_w = (const float*)d_in[11];
  const float* Wu_w = (const float*)d_in[12];

  float* h_new = (float*)d_out;                          // [B,NV,D]
  float* z_new = (float*)d_out + (long)BB * NV * DD;     // [B,NV,2D]

  const size_t MB = 1u << 20;
  char* W = (char*)d_ws;
  // ---- workspace layout with aliasing (total ~465 MB) ----
  _Float16* vhi  = (_Float16*)(W + 0 * MB);     // 32 MB, alive to end (Vv GEMM, f uses fp32 v)
  _Float16* vlo  = (_Float16*)(W + 32 * MB);    // 32 MB
  _Float16* hhi  = (_Float16*)(W + 64 * MB);    // 32 MB (also h16 for Hht GEMM)
  _Float16* hlo  = (_Float16*)(W + 96 * MB);    // 32 MB
  _Float16* z16  = (_Float16*)(W + 128 * MB);   // 64 MB
  _Float16* qvhi = (_Float16*)(W + 192 * MB);   // 2 MB
  _Float16* qvlo = (_Float16*)(W + 194 * MB);
  _Float16* khhi = (_Float16*)(W + 196 * MB);
  _Float16* khlo = (_Float16*)(W + 198 * MB);
  _Float16* Wv16 = (_Float16*)(W + 200 * MB);
  _Float16* Wh16 = (_Float16*)(W + 202 * MB);
  _Float16* Wz16 = (_Float16*)(W + 204 * MB);   // 4 MB
  float*    Q32  = (float*)(W + 208 * MB);      // 64 MB; att32 aliases after Q split
  float*    att32 = (float*)(W + 208 * MB);
  float*    K32  = (float*)(W + 272 * MB);      // 64 MB; dead after K split
  _Float16* Vv16 = (_Float16*)(W + 272 * MB);   // 32 MB (over K32 lo half)
  _Float16* Zz16 = (_Float16*)(W + 304 * MB);   // 32 MB (over K32 hi half)
  _Float16* Qhi  = (_Float16*)(W + 336 * MB);   // 32 MB; P16 aliases after att
  _Float16* P16  = (_Float16*)(W + 336 * MB);
  _Float16* Qlo  = (_Float16*)(W + 368 * MB);   // 32 MB; Hht16 aliases after att
  _Float16* Hht16 = (_Float16*)(W + 368 * MB);
  _Float16* Khi  = (_Float16*)(W + 400 * MB);   // 32 MB ┐ Hv32 (64 MB) aliases after att
  _Float16* Klo  = (_Float16*)(W + 432 * MB);   // 32 MB ┘
  float*    Hv32 = (float*)(W + 400 * MB);
  float*    u_buf = (float*)(W + 464 * MB);     // 64 KB
  float*    p_buf = (float*)(W + 464 * MB + 65536);
  float*    f_buf = (float*)(W + 464 * MB + 2 * 65536);

  const long nVD = (long)BB * NV * DD;  // 16M elements
  const long s1M = (long)NV * DD;       // per-batch stride

  auto cast = [&](const float* src, _Float16* dst, long n) {
    long n4 = n / 4;
    cast_k<<<(int)((n4 + 255) / 256), 256, 0, stream>>>(src, dst, n4);
  };
  auto split = [&](const float* src, _Float16* hi, _Float16* lo, long n) {
    long n4 = n / 4;
    split_k<<<(int)((n4 + 255) / 256), 256, 0, stream>>>(src, hi, lo, n4);
  };

  // --- casts & splits of inputs ---
  split(v, vhi, vlo, nVD);
  split(h, hhi, hlo, nVD);
  cast(z, z16, nVD * 2);
  split(qv_w, qvhi, qvlo, (long)DD * DD);
  split(kh_w, khhi, khlo, (long)DD * DD);
  cast(Wv_w, Wv16, (long)DD * DD);
  cast(Wh_w, Wh16, (long)DD * DD);
  cast(Wz_w, Wz16, (long)DD * 2 * DD);

  const dim3 gBig(8, 128, 1);   // [16384,1024] C
  const dim3 gBat(8, 8, BB);    // per-batch [1024,1024] C

  // --- Q = v @ qv^T + b, split precision, fp32 result ---
  gemm_nt_k<float, false><<<gBig, 256, 0, stream>>>(vhi, qvhi, Q32, qv_b, DD, DD, 0, 0, 0);
  gemm_nt_k<float, true ><<<gBig, 256, 0, stream>>>(vlo, qvhi, Q32, nullptr, DD, DD, 0, 0, 0);
  gemm_nt_k<float, true ><<<gBig, 256, 0, stream>>>(vhi, qvlo, Q32, nullptr, DD, DD, 0, 0, 0);
  // --- K = h @ kh^T, split precision, fp32 result ---
  gemm_nt_k<float, false><<<gBig, 256, 0, stream>>>(hhi, khhi, K32, nullptr, DD, DD, 0, 0, 0);
  gemm_nt_k<float, true ><<<gBig, 256, 0, stream>>>(hlo, khhi, K32, nullptr, DD, DD, 0, 0, 0);
  gemm_nt_k<float, true ><<<gBig, 256, 0, stream>>>(hhi, khlo, K32, nullptr, DD, DD, 0, 0, 0);
  mask_key_k<<<(BB * NH + 255) / 256, 256, 0, stream>>>(K32, h_mask);
  // --- split Q, K to hi/lo fp16 ---
  split(Q32, Qhi, Qlo, nVD);
  split(K32, Khi, Klo, nVD);
  // --- Vv, Zz (single fp16 precision; over dead K32 region) ---
  gemm_nt_k<_Float16, false><<<gBig, 256, 0, stream>>>(vhi, Wv16, Vv16, Wv_b, DD, DD, 0, 0, 0);
  gemm_nt_k<_Float16, false><<<gBig, 256, 0, stream>>>(z16, Wz16, Zz16, nullptr, DD, 2 * DD, 0, 0, 0);
  // --- att = Q @ K^T, split precision, fp32 (aliases dead Q32) ---
  gemm_nt_k<float, false><<<gBat, 256, 0, stream>>>(Qhi, Khi, att32, nullptr, NH, DD, s1M, s1M, s1M);
  gemm_nt_k<float, true ><<<gBat, 256, 0, stream>>>(Qlo, Khi, att32, nullptr, NH, DD, s1M, s1M, s1M);
  gemm_nt_k<float, true ><<<gBat, 256, 0, stream>>>(Qhi, Klo, att32, nullptr, NH, DD, s1M, s1M, s1M);
  // --- P = softmax(att) rows (P16 aliases dead Qhi) ---
  softmax_rows_k<<<BB * NV, 256, 0, stream>>>(att32, P16);
  // --- Hht[b][d,n] = Wh @ h[b]^T (aliases dead Qlo) ---
  gemm_nt_k<_Float16, false><<<gBat, 256, 0, stream>>>(Wh16, hhi, Hht16, nullptr, NH, DD, 0, s1M, s1M);
  // --- Hv[b] = P[b] @ Hht[b]^T, fp32 out (aliases dead Khi/Klo) ---
  gemm_nt_k<float, false><<<gBat, 256, 0, stream>>>(P16, Hht16, Hv32, nullptr, DD, NH, s1M, s1M, s1M);
  // --- s, u ---
  s_u_k<<<BB * NV, 256, 0, stream>>>(Vv16, Hv32, Zz16, Wu_w, z_new, u_buf);
  // --- p = softmax(u) per batch ---
  u_softmax_k<<<BB, 256, 0, stream>>>(u_buf, v_mask, p_buf);
  // --- f = p @ v (rank-1 across i) ---
  hipMemsetAsync(f_buf, 0, (long)BB * DD * 4, stream);
  f_part_k<<<dim3(4, BB, 8), 256, 0, stream>>>(p_buf, v, f_buf);
  // --- broadcast f -> h_new and z_new[:, D:] ---
  bcast_k<<<(int)(nVD / 4 / 256), 256, 0, stream>>>(f_buf, h_new, z_new);
}

// Round 3
// 1191.456 us; speedup vs baseline: 1.4576x; 1.4576x over previous
//
#include <hip/hip_runtime.h>

#define BB 16
#define NV 1024
#define NH 1024
#define DD 1024

typedef _Float16 f16x8 __attribute__((ext_vector_type(8)));
typedef _Float16 f16x4 __attribute__((ext_vector_type(4)));
typedef float f32x4 __attribute__((ext_vector_type(4)));

// ---------------- cast fp32 -> fp16 ----------------
__global__ __launch_bounds__(256) void cast_k(const float* __restrict__ in,
                                              _Float16* __restrict__ out, long n4) {
  long i = (long)blockIdx.x * 256 + threadIdx.x;
  long stride = (long)gridDim.x * 256;
  for (; i < n4; i += stride) {
    float4 x = ((const float4*)in)[i];
    f16x4 o;
    o[0] = (_Float16)x.x; o[1] = (_Float16)x.y;
    o[2] = (_Float16)x.z; o[3] = (_Float16)x.w;
    ((f16x4*)out)[i] = o;
  }
}

// ---------------- split fp32 -> (hi, lo) fp16 pair ----------------
__global__ __launch_bounds__(256) void split_k(const float* __restrict__ in,
                                               _Float16* __restrict__ hi,
                                               _Float16* __restrict__ lo, long n4) {
  long i = (long)blockIdx.x * 256 + threadIdx.x;
  long stride = (long)gridDim.x * 256;
  for (; i < n4; i += stride) {
    float4 x = ((const float4*)in)[i];
    f16x4 h, l;
    h[0] = (_Float16)x.x; h[1] = (_Float16)x.y;
    h[2] = (_Float16)x.z; h[3] = (_Float16)x.w;
    l[0] = (_Float16)(x.x - (float)h[0]);
    l[1] = (_Float16)(x.y - (float)h[1]);
    l[2] = (_Float16)(x.z - (float)h[2]);
    l[3] = (_Float16)(x.w - (float)h[3]);
    ((f16x4*)hi)[i] = h;
    ((f16x4*)lo)[i] = l;
  }
}

// ---------------- async global->LDS (16B/lane) ----------------
__device__ inline void gl_lds16(const _Float16* g, _Float16* l) {
  __builtin_amdgcn_global_load_lds((__attribute__((address_space(1))) void*)g,
                                   (__attribute__((address_space(3))) void*)l,
                                   16, 0, 0);
}

// XCD-aware decode: 1024 blocks, N fixed = 1024 (8 bn tiles).
// NB==1:  M=16384 (128 bm tiles): each XCD gets a contiguous band of 16 bm x 8 bn.
// NB==16: per-batch 1024x1024 (8 bm): each XCD gets 2 whole batches.
__device__ inline void decode_tiles(int flat, int NB, int& bm, int& bn, int& bz) {
  int xcd = flat & 7, j = flat >> 3;  // j in [0,128)
  if (NB == 1) {
    bz = 0;
    bm = xcd * 16 + (j >> 3);
    bn = j & 7;
  } else {
    bz = xcd * 2 + (j >> 6);
    int r = j & 63;
    bm = r >> 3;
    bn = r & 7;
  }
}

// ---------------- single-precision NT GEMM: C[M,1024] = A[M,K] * B[1024,K]^T (+bias)
template <typename CT>
__global__ __launch_bounds__(256) void gemm_nt_k(
    const _Float16* __restrict__ A, const _Float16* __restrict__ B,
    CT* __restrict__ C, const float* __restrict__ bias,
    int K, int NB, long sA, long sB, long sC) {
  __shared__ _Float16 lA[128 * 32];
  __shared__ _Float16 lB[128 * 32];
  const int tid = threadIdx.x;
  const int w = tid >> 6, l = tid & 63;
  int bm, bn, bz;
  decode_tiles(blockIdx.x, NB, bm, bn, bz);
  const _Float16* Ab = A + (long)bz * sA;
  const _Float16* Bb = B + (long)bz * sB;
  CT* Cb = C + (long)bz * sC;

  const int c0 = 2 * w;
  const int srow = l >> 2, scol = (l & 3) * 8;
  const _Float16* pA = Ab + (long)(bm * 128 + c0 * 16 + srow) * K + scol;
  const _Float16* pB = Bb + (long)(bn * 128 + c0 * 16 + srow) * K + scol;
  const long rs16 = (long)16 * K;
  _Float16* dA = lA + c0 * 16 * 32;
  _Float16* dB = lB + c0 * 16 * 32;

  f32x4 acc[4][4] = {};
  const int wm = w >> 1, wn = w & 1;
  const int fr = l & 15, fq = l >> 4;
  const int aoff = (wm * 64 + fr) * 32 + fq * 8;
  const int boff = (wn * 64 + fr) * 32 + fq * 8;

  for (int kt = 0; kt < K; kt += 32) {
    gl_lds16(pA, dA);
    gl_lds16(pA + rs16, dA + 512);
    gl_lds16(pB, dB);
    gl_lds16(pB + rs16, dB + 512);
    pA += 32; pB += 32;
    __syncthreads();
    f16x8 af[4], bf[4];
#pragma unroll
    for (int r = 0; r < 4; ++r) af[r] = *(const f16x8*)&lA[aoff + r * 512];
#pragma unroll
    for (int c = 0; c < 4; ++c) bf[c] = *(const f16x8*)&lB[boff + c * 512];
#pragma unroll
    for (int r = 0; r < 4; ++r)
#pragma unroll
      for (int c = 0; c < 4; ++c)
        acc[r][c] = __builtin_amdgcn_mfma_f32_16x16x32_f16(af[r], bf[c], acc[r][c], 0, 0, 0);
    __syncthreads();
  }

#pragma unroll
  for (int r = 0; r < 4; ++r) {
    const int grow = bm * 128 + wm * 64 + r * 16 + fq * 4;
#pragma unroll
    for (int c = 0; c < 4; ++c) {
      const int gcol = bn * 128 + wn * 64 + c * 16 + fr;
      const float bv = bias ? bias[gcol] : 0.0f;
#pragma unroll
      for (int e = 0; e < 4; ++e)
        Cb[(long)(grow + e) * 1024 + gcol] = (CT)(acc[r][c][e] + bv);
    }
  }
}

// ---------------- fused 3-term split GEMM:
// C = Ahi*Bhi^T + Alo*Bhi^T + Ahi*Blo^T (+bias) ; optional row-mask -> -30000
// SPLIT_OUT: write (Chi, Clo) fp16 pair; else write Cf fp32.
template <bool SPLIT_OUT>
__global__ __launch_bounds__(256) void gemm3_nt_k(
    const _Float16* __restrict__ Ahi, const _Float16* __restrict__ Alo,
    const _Float16* __restrict__ Bhi, const _Float16* __restrict__ Blo,
    float* __restrict__ Cf, _Float16* __restrict__ Chi, _Float16* __restrict__ Clo,
    const float* __restrict__ bias, const int* __restrict__ mask,
    int K, int NB, long sA, long sB, long sC) {
  __shared__ _Float16 lAh[128 * 32];
  __shared__ _Float16 lAl[128 * 32];
  __shared__ _Float16 lBh[128 * 32];
  __shared__ _Float16 lBl[128 * 32];
  const int tid = threadIdx.x;
  const int w = tid >> 6, l = tid & 63;
  int bm, bn, bz;
  decode_tiles(blockIdx.x, NB, bm, bn, bz);

  const int c0 = 2 * w;
  const int srow = l >> 2, scol = (l & 3) * 8;
  const long arow = (long)(bm * 128 + c0 * 16 + srow) * K + scol + (long)bz * sA;
  const long brow = (long)(bn * 128 + c0 * 16 + srow) * K + scol + (long)bz * sB;
  const _Float16* pAh = Ahi + arow;
  const _Float16* pAl = Alo + arow;
  const _Float16* pBh = Bhi + brow;
  const _Float16* pBl = Blo + brow;
  const long rs16 = (long)16 * K;
  const int dofs = c0 * 512;

  f32x4 acc[4][4] = {};
  const int wm = w >> 1, wn = w & 1;
  const int fr = l & 15, fq = l >> 4;
  const int aoff = (wm * 64 + fr) * 32 + fq * 8;
  const int boff = (wn * 64 + fr) * 32 + fq * 8;

  for (int kt = 0; kt < K; kt += 32) {
    gl_lds16(pAh, lAh + dofs);
    gl_lds16(pAh + rs16, lAh + dofs + 512);
    gl_lds16(pAl, lAl + dofs);
    gl_lds16(pAl + rs16, lAl + dofs + 512);
    gl_lds16(pBh, lBh + dofs);
    gl_lds16(pBh + rs16, lBh + dofs + 512);
    gl_lds16(pBl, lBl + dofs);
    gl_lds16(pBl + rs16, lBl + dofs + 512);
    pAh += 32; pAl += 32; pBh += 32; pBl += 32;
    __syncthreads();
    f16x8 ah[4], al[4], bh[4], bl[4];
#pragma unroll
    for (int r = 0; r < 4; ++r) {
      ah[r] = *(const f16x8*)&lAh[aoff + r * 512];
      al[r] = *(const f16x8*)&lAl[aoff + r * 512];
    }
#pragma unroll
    for (int c = 0; c < 4; ++c) {
      bh[c] = *(const f16x8*)&lBh[boff + c * 512];
      bl[c] = *(const f16x8*)&lBl[boff + c * 512];
    }
#pragma unroll
    for (int r = 0; r < 4; ++r)
#pragma unroll
      for (int c = 0; c < 4; ++c) {
        acc[r][c] = __builtin_amdgcn_mfma_f32_16x16x32_f16(ah[r], bh[c], acc[r][c], 0, 0, 0);
        acc[r][c] = __builtin_amdgcn_mfma_f32_16x16x32_f16(al[r], bh[c], acc[r][c], 0, 0, 0);
        acc[r][c] = __builtin_amdgcn_mfma_f32_16x16x32_f16(ah[r], bl[c], acc[r][c], 0, 0, 0);
      }
    __syncthreads();
  }

#pragma unroll
  for (int r = 0; r < 4; ++r) {
    const int grow = bm * 128 + wm * 64 + r * 16 + fq * 4;
#pragma unroll
    for (int c = 0; c < 4; ++c) {
      const int gcol = bn * 128 + wn * 64 + c * 16 + fr;
      const float bv = bias ? bias[gcol] : 0.0f;
#pragma unroll
      for (int e = 0; e < 4; ++e) {
        float val = acc[r][c][e] + bv;
        if (mask && mask[grow + e] == 0) val = -30000.0f;
        const long idx = (long)(grow + e) * 1024 + gcol + (long)bz * sC;
        if (SPLIT_OUT) {
          _Float16 hi = (_Float16)val;
          Chi[idx] = hi;
          Clo[idx] = (_Float16)(val - (float)hi);
        } else {
          Cf[idx] = val;
        }
      }
    }
  }
}

// ---------------- wave/block reduce helpers ----------------
__device__ inline float wave_max(float v) {
#pragma unroll
  for (int o = 32; o > 0; o >>= 1) v = fmaxf(v, __shfl_xor(v, o, 64));
  return v;
}
__device__ inline float wave_sum(float v) {
#pragma unroll
  for (int o = 32; o > 0; o >>= 1) v += __shfl_xor(v, o, 64);
  return v;
}

// ---------------- row softmax: att fp32 [rows,1024] -> P fp16 ----------------
__global__ __launch_bounds__(256) void softmax_rows_k(const float* __restrict__ att,
                                                      _Float16* __restrict__ P) {
  __shared__ float red[4];
  long row = blockIdx.x;
  int t = threadIdx.x, w = t >> 6;
  float4 x = ((const float4*)(att + row * 1024))[t];
  float m = fmaxf(fmaxf(x.x, x.y), fmaxf(x.z, x.w));
  m = wave_max(m);
  if ((t & 63) == 0) red[w] = m;
  __syncthreads();
  m = fmaxf(fmaxf(red[0], red[1]), fmaxf(red[2], red[3]));
  float e0 = expf(x.x - m), e1 = expf(x.y - m), e2 = expf(x.z - m), e3 = expf(x.w - m);
  float s = wave_sum(e0 + e1 + e2 + e3);
  __syncthreads();
  if ((t & 63) == 0) red[w] = s;
  __syncthreads();
  float inv = 1.0f / (red[0] + red[1] + red[2] + red[3]);
  f16x4 o;
  o[0] = (_Float16)(e0 * inv); o[1] = (_Float16)(e1 * inv);
  o[2] = (_Float16)(e2 * inv); o[3] = (_Float16)(e3 * inv);
  ((f16x4*)(P + row * 1024))[t] = o;
}

// ---------------- s = sigmoid(vv+hv+zz) -> z_new[:, :D]; u = s . Wu ----------------
__global__ __launch_bounds__(256) void s_u_k(const _Float16* __restrict__ Vv,
                                             const float* __restrict__ Hv,
                                             const _Float16* __restrict__ Zz,
                                             const float* __restrict__ Wu,
                                             float* __restrict__ zout,
                                             float* __restrict__ u) {
  __shared__ float red[4];
  long row = blockIdx.x;
  int t = threadIdx.x, w = t >> 6;
  f16x4 a = ((const f16x4*)(Vv + row * 1024))[t];
  float4 b = ((const float4*)(Hv + row * 1024))[t];
  f16x4 c = ((const f16x4*)(Zz + row * 1024))[t];
  float4 wu = ((const float4*)Wu)[t];
  float4 sv;
  sv.x = 1.0f / (1.0f + expf(-((float)a[0] + b.x + (float)c[0])));
  sv.y = 1.0f / (1.0f + expf(-((float)a[1] + b.y + (float)c[1])));
  sv.z = 1.0f / (1.0f + expf(-((float)a[2] + b.z + (float)c[2])));
  sv.w = 1.0f / (1.0f + expf(-((float)a[3] + b.w + (float)c[3])));
  ((float4*)(zout + row * 2048))[t] = sv;
  float part = sv.x * wu.x + sv.y * wu.y + sv.z * wu.z + sv.w * wu.w;
  part = wave_sum(part);
  if ((t & 63) == 0) red[w] = part;
  __syncthreads();
  if (t == 0) u[row] = red[0] + red[1] + red[2] + red[3];
}

// ---------------- per-batch softmax over u (masked) ----------------
__global__ __launch_bounds__(256) void u_softmax_k(const float* __restrict__ u,
                                                   const int* __restrict__ vmask,
                                                   float* __restrict__ p) {
  __shared__ float red[4];
  int b = blockIdx.x, t = threadIdx.x, w = t >> 6;
  float4 uv = ((const float4*)(u + b * 1024))[t];
  int4 mv = ((const int4*)(vmask + b * 1024))[t];
  float l0 = mv.x ? uv.x : -1e30f;
  float l1 = mv.y ? uv.y : -1e30f;
  float l2 = mv.z ? uv.z : -1e30f;
  float l3 = mv.w ? uv.w : -1e30f;
  float m = wave_max(fmaxf(fmaxf(l0, l1), fmaxf(l2, l3)));
  if ((t & 63) == 0) red[w] = m;
  __syncthreads();
  m = fmaxf(fmaxf(red[0], red[1]), fmaxf(red[2], red[3]));
  float e0 = expf(l0 - m), e1 = expf(l1 - m), e2 = expf(l2 - m), e3 = expf(l3 - m);
  float s = wave_sum(e0 + e1 + e2 + e3);
  __syncthreads();
  if ((t & 63) == 0) red[w] = s;
  __syncthreads();
  float inv = 1.0f / (red[0] + red[1] + red[2] + red[3]);
  float4 o = make_float4(e0 * inv, e1 * inv, e2 * inv, e3 * inv);
  ((float4*)(p + b * 1024))[t] = o;
}

// ---------------- f[b,d] = sum_j p[b,j] * v[b,j,d] (partials via atomics) ----------------
__global__ __launch_bounds__(256) void f_part_k(const float* __restrict__ p,
                                               const float* __restrict__ v,
                                               float* __restrict__ f) {
  int d = blockIdx.x * 256 + threadIdx.x;  // gridDim.x = 4
  int b = blockIdx.y;                      // 16
  int jc = blockIdx.z;                     // 8 chunks of 128
  const float* vb = v + ((long)b * NV + jc * 128) * DD + d;
  const float* pb = p + b * NV + jc * 128;
  float acc = 0.0f;
#pragma unroll 4
  for (int j = 0; j < 128; ++j) acc = fmaf(pb[j], vb[(long)j * DD], acc);
  atomicAdd(&f[b * DD + d], acc);
}

// ---------------- broadcast f into h_new and z_new[:, D:] ----------------
__global__ __launch_bounds__(256) void bcast_k(const float* __restrict__ f,
                                               float* __restrict__ hout,
                                               float* __restrict__ zout) {
  long idx = (long)blockIdx.x * 256 + threadIdx.x;  // float4 units
  int d4 = (int)(idx & 255);
  long bn = idx >> 8;
  int b = (int)(bn >> 10);
  float4 val = ((const float4*)f)[(b << 8) + d4];
  ((float4*)hout)[idx] = val;
  ((float4*)zout)[bn * 512 + 256 + d4] = val;
}

// ---------------- host ----------------
extern "C" void kernel_launch(void* const* d_in, const int* in_sizes, int n_in,
                              void* d_out, int out_size, void* d_ws, size_t ws_size,
                              hipStream_t stream) {
  const float* v = (const float*)d_in[0];
  const float* h = (const float*)d_in[1];
  const float* z = (const float*)d_in[2];
  const int* v_mask = (const int*)d_in[3];
  const int* h_mask = (const int*)d_in[4];
  const float* Wv_w = (const float*)d_in[5];
  const float* Wv_b = (const float*)d_in[6];
  const float* Wh_w = (const float*)d_in[7];
  const float* qv_w = (const float*)d_in[8];
  const float* qv_b = (const float*)d_in[9];
  const float* kh_w = (const float*)d_in[10];
  const float* Wz_w = (const float*)d_in[11];
  const float* Wu_w = (const float*)d_in[12];

  float* h_new = (float*)d_out;
  float* z_new = (float*)d_out + (long)BB * NV * DD;

  const size_t MB = 1u << 20;
  char* W = (char*)d_ws;
  // ---- workspace layout with aliasing (~401 MB) ----
  _Float16* vhi  = (_Float16*)(W + 0 * MB);     // alive to end
  _Float16* vlo  = (_Float16*)(W + 32 * MB);    // dead after Q -> P16
  _Float16* P16  = (_Float16*)(W + 32 * MB);
  _Float16* hhi  = (_Float16*)(W + 64 * MB);    // alive through Hht
  _Float16* hlo  = (_Float16*)(W + 96 * MB);    // dead after K -> Hht16
  _Float16* Hht16 = (_Float16*)(W + 96 * MB);
  _Float16* z16  = (_Float16*)(W + 128 * MB);   // 64 MB
  _Float16* qvhi = (_Float16*)(W + 192 * MB);
  _Float16* qvlo = (_Float16*)(W + 194 * MB);
  _Float16* khhi = (_Float16*)(W + 196 * MB);
  _Float16* khlo = (_Float16*)(W + 198 * MB);
  _Float16* Wv16 = (_Float16*)(W + 200 * MB);
  _Float16* Wh16 = (_Float16*)(W + 202 * MB);
  _Float16* Wz16 = (_Float16*)(W + 204 * MB);   // 4 MB
  _Float16* Qhi  = (_Float16*)(W + 208 * MB);   // dead after att -> Vv16
  _Float16* Vv16 = (_Float16*)(W + 208 * MB);
  _Float16* Qlo  = (_Float16*)(W + 240 * MB);   // dead after att -> Zz16
  _Float16* Zz16 = (_Float16*)(W + 240 * MB);
  _Float16* Khi  = (_Float16*)(W + 272 * MB);   // dead after att ┐
  _Float16* Klo  = (_Float16*)(W + 304 * MB);   //                ┘ -> Hv32 (64MB)
  float*    Hv32 = (float*)(W + 272 * MB);
  float*    att32 = (float*)(W + 336 * MB);     // 64 MB
  float*    u_buf = (float*)(W + 400 * MB);
  float*    p_buf = (float*)(W + 400 * MB + 65536);
  float*    f_buf = (float*)(W + 400 * MB + 2 * 65536);

  const long nVD = (long)BB * NV * DD;  // 16M
  const long s1M = (long)NV * DD;

  auto cast = [&](const float* src, _Float16* dst, long n) {
    long n4 = n / 4;
    cast_k<<<(int)((n4 + 255) / 256), 256, 0, stream>>>(src, dst, n4);
  };
  auto split = [&](const float* src, _Float16* hi, _Float16* lo, long n) {
    long n4 = n / 4;
    split_k<<<(int)((n4 + 255) / 256), 256, 0, stream>>>(src, hi, lo, n4);
  };

  // --- casts & splits ---
  split(v, vhi, vlo, nVD);
  split(h, hhi, hlo, nVD);
  cast(z, z16, nVD * 2);
  split(qv_w, qvhi, qvlo, (long)DD * DD);
  split(kh_w, khhi, khlo, (long)DD * DD);
  cast(Wv_w, Wv16, (long)DD * DD);
  cast(Wh_w, Wh16, (long)DD * DD);
  cast(Wz_w, Wz16, (long)DD * 2 * DD);

  // --- Q = v @ qv^T + b (split-precision, split output) ---
  gemm3_nt_k<true><<<1024, 256, 0, stream>>>(vhi, vlo, qvhi, qvlo,
      nullptr, Qhi, Qlo, qv_b, nullptr, DD, 1, 0, 0, 0);
  // --- K = h @ kh^T (split-precision, split output, h_mask folded) ---
  gemm3_nt_k<true><<<1024, 256, 0, stream>>>(hhi, hlo, khhi, khlo,
      nullptr, Khi, Klo, nullptr, h_mask, DD, 1, 0, 0, 0);
  // --- att[b] = Q[b] @ K[b]^T (split-precision, fp32 out) ---
  gemm3_nt_k<false><<<1024, 256, 0, stream>>>(Qhi, Qlo, Khi, Klo,
      att32, nullptr, nullptr, nullptr, nullptr, DD, BB, s1M, s1M, s1M);
  // --- P = softmax(att) rows (P16 over dead vlo) ---
  softmax_rows_k<<<BB * NV, 256, 0, stream>>>(att32, P16);
  // --- Hht[b][d,n] = Wh @ h[b]^T (over dead hlo) ---
  gemm_nt_k<_Float16><<<1024, 256, 0, stream>>>(Wh16, hhi, Hht16, nullptr, DD, BB, 0, s1M, s1M);
  // --- Vv = v @ Wv^T + b (over dead Qhi) ---
  gemm_nt_k<_Float16><<<1024, 256, 0, stream>>>(vhi, Wv16, Vv16, Wv_b, DD, 1, 0, 0, 0);
  // --- Zz = z @ Wz^T, K=2048 (over dead Qlo) ---
  gemm_nt_k<_Float16><<<1024, 256, 0, stream>>>(z16, Wz16, Zz16, nullptr, 2 * DD, 1, 0, 0, 0);
  // --- Hv[b] = P[b] @ Hht[b]^T, fp32 out (over dead Khi/Klo) ---
  gemm_nt_k<float><<<1024, 256, 0, stream>>>(P16, Hht16, Hv32, nullptr, NH, BB, s1M, s1M, s1M);
  // --- s, u ---
  s_u_k<<<BB * NV, 256, 0, stream>>>(Vv16, Hv32, Zz16, Wu_w, z_new, u_buf);
  // --- p = softmax(u) per batch ---
  u_softmax_k<<<BB, 256, 0, stream>>>(u_buf, v_mask, p_buf);
  // --- f = p @ v ---
  hipMemsetAsync(f_buf, 0, (long)BB * DD * 4, stream);
  f_part_k<<<dim3(4, BB, 8), 256, 0, stream>>>(p_buf, v, f_buf);
  // --- broadcast ---
  bcast_k<<<(int)(nVD / 4 / 256), 256, 0, stream>>>(f_buf, h_new, z_new);
}